// Round 12
// baseline (282.693 us; speedup 1.0000x reference)
//
#include <hip/hip_runtime.h>
#include <hip/hip_bf16.h>
#include <stdint.h>

typedef __bf16 bf16x8 __attribute__((ext_vector_type(8)));
typedef __bf16 bf16x4 __attribute__((ext_vector_type(4)));
typedef float  f32x4  __attribute__((ext_vector_type(4)));

#define MFMA16(a, b, c) __builtin_amdgcn_mfma_f32_16x16x32_bf16((a), (b), (c), 0, 0, 0)

constexpr int BATCH = 4;
constexpr int TSEQ  = 2048;
constexpr int CDIM  = 1024;
constexpr int NHEAD = 16;
constexpr int HSZ   = 64;
constexpr size_t HEADELEMS = (size_t)BATCH * NHEAD * TSEQ * HSZ;  // 8388608

constexpr int LDF = 72;  // flash LDS stride (144 B)

// direct global->LDS DMA, 16 B per lane; LDS dest = wave-uniform base + lane*16
__device__ __forceinline__ void load_lds_128(const __bf16* g, __bf16* l) {
    __builtin_amdgcn_global_load_lds(
        (const __attribute__((address_space(1))) unsigned int*)g,
        (__attribute__((address_space(3))) unsigned int*)l,
        16, 0, 0);
}

// ---------------------------------------------------------------------------
// Fused prep (VALIDATED r10): one dispatch = {fp32->bf16 convert of x,
// W_attn transpose, W_proj transpose}. Grid sections, whole blocks per
// branch, no divergence.
// ---------------------------------------------------------------------------
__global__ __launch_bounds__(256)
void prep_fused(const float* __restrict__ x, __bf16* __restrict__ cx,
                const float* __restrict__ wa, __bf16* __restrict__ cwaT,
                const float* __restrict__ wp, __bf16* __restrict__ cwpT)
{
    __shared__ __bf16 tile[32][33];
    const int blk = blockIdx.x;

    if (blk < 4096) {
        const int i0 = (blk * 256 + (int)threadIdx.x) * 8;   // < 8388608
        float4 a = *(const float4*)(x + i0);
        float4 b = *(const float4*)(x + i0 + 4);
        bf16x8 o;
        o[0] = (__bf16)a.x; o[1] = (__bf16)a.y; o[2] = (__bf16)a.z; o[3] = (__bf16)a.w;
        o[4] = (__bf16)b.x; o[5] = (__bf16)b.y; o[6] = (__bf16)b.z; o[7] = (__bf16)b.w;
        *(bf16x8*)(cx + i0) = o;
        return;
    }

    const float* src;  __bf16* dst;  int K, N, bidx;
    if (blk < 7168) { src = wa; dst = cwaT; K = 1024; N = 3072; bidx = blk - 4096; }
    else            { src = wp; dst = cwpT; K = 1024; N = 1024; bidx = blk - 7168; }
    const int nbx = N >> 5;
    const int n0 = (bidx % nbx) * 32, k0 = (bidx / nbx) * 32;
    const int tx = threadIdx.x & 31, ty = threadIdx.x >> 5;   // 32 x 8
    #pragma unroll
    for (int i = 0; i < 32; i += 8)
        tile[ty + i][tx] = (__bf16)src[(size_t)(k0 + ty + i) * N + n0 + tx];  // tile[k][n]
    __syncthreads();
    #pragma unroll
    for (int i = 0; i < 32; i += 8)
        dst[(size_t)(n0 + ty + i) * K + k0 + tx] = tile[tx][ty + i];          // dst[n][k]
}

// ---------------------------------------------------------------------------
// QKV GEMM -- ROUND-12: 256x128 block tile, 4 waves, per-wave 128x64.
// Model (r11 post-mortem): old 64x64/wave kernel is LDS-read-BW-bound:
// 96 ds_read_b128 per CU per K-step at ~12cyc (m134) = 1152 cyc vs 240 cyc
// MFMA -> predicted 21% MfmaUtil, measured 22%. Reads/MFMA scales as
// (m+n)/(m*n) per wave: 128x64/wave = 0.375 vs 0.5 -> same 96 reads/CU/step
// now feed 256 MFMAs. LDS 3buf x 24KB = 72KB -> 2 blocks/CU (8 waves/CU).
// Same VALIDATED counted-vmcnt pipe: depth-2 prefetch, 3 buffers,
// vmcnt(6) per iter (6 loads/wave/tile, never 0 mid-loop), raw s_barrier +
// sched_barrier(0); same ordering proof as r5 (per-wave ledger: outstanding
// = tiles {it,it+1} = 12 -> vmcnt(6) drains tile it; barrier publishes).
// Grid 24x32 = 768 (%8==0 -> T1 swizzle bijective).
// Epilogue: scatter q[b,h,t,d], k[b,h,t,d], v transposed [b,h,d,t] (bf16).
// ---------------------------------------------------------------------------
__global__ __launch_bounds__(256, 2)
void gemm_qkv_pipe(const __bf16* __restrict__ A, const __bf16* __restrict__ BT,
                   const float* __restrict__ bias, __bf16* __restrict__ outp,
                   int M, int N, int K)
{
    __shared__ __bf16 As[3][256 * 32];   // [buf][row][k], unpadded
    __shared__ __bf16 Bs[3][128 * 32];

    const int t    = threadIdx.x;
    const int wave = t >> 6, lane = t & 63;
    const int quad = lane >> 4, l16 = lane & 15;

    // T1 XCD swizzle: hw-dispatch id -> logical tile id, contiguous per XCD
    const int nbx = (int)gridDim.x;
    int lin = (int)blockIdx.y * nbx + (int)blockIdx.x;
    {
        const int cpx = (nbx * (int)gridDim.y) >> 3;   // nwg % 8 == 0
        lin = (lin & 7) * cpx + (lin >> 3);
    }
    const int bm = (lin / nbx) * 256, bn = (lin % nbx) * 128;
    const int wm = (wave >> 1) * 128, wn = (wave & 1) * 64;   // per-wave 128x64

    const int lrow = lane >> 2, lchunk = lane & 3;

    f32x4 acc[8][4];
    #pragma unroll
    for (int i = 0; i < 8; ++i)
        #pragma unroll
        for (int j = 0; j < 4; ++j)
            acc[i][j] = (f32x4){0.f, 0.f, 0.f, 0.f};

    // staging: wave stages A rows [wave*64, wave*64+64) as 4 chunks of 16,
    // and B rows [wave*32, wave*32+32) as 2 chunks of 16. 6 loads/wave/tile.
    const __bf16* ga[4];
    const __bf16* gb[2];
    #pragma unroll
    for (int c = 0; c < 4; ++c)
        ga[c] = A + (size_t)(bm + wave * 64 + c * 16 + lrow) * K + 8 * lchunk;
    #pragma unroll
    for (int c = 0; c < 2; ++c)
        gb[c] = BT + (size_t)(bn + wave * 32 + c * 16 + lrow) * K + 8 * lchunk;

    const int nk = K >> 5;

#define STAGE(buf, kofs) do { \
    load_lds_128(ga[0] + (kofs), &As[buf][(wave * 4 + 0) * 512]); \
    load_lds_128(ga[1] + (kofs), &As[buf][(wave * 4 + 1) * 512]); \
    load_lds_128(ga[2] + (kofs), &As[buf][(wave * 4 + 2) * 512]); \
    load_lds_128(ga[3] + (kofs), &As[buf][(wave * 4 + 3) * 512]); \
    load_lds_128(gb[0] + (kofs), &Bs[buf][(wave * 2 + 0) * 512]); \
    load_lds_128(gb[1] + (kofs), &Bs[buf][(wave * 2 + 1) * 512]); } while (0)

    // prologue: tiles 0 and 1 in flight
    STAGE(0, 0);
    if (nk > 1) STAGE(1, 32);

    int cur = 0;
    for (int it = 0; it < nk; ++it) {
        if (it + 1 < nk) asm volatile("s_waitcnt vmcnt(6)" ::: "memory");
        else             asm volatile("s_waitcnt vmcnt(0)" ::: "memory");
        __builtin_amdgcn_s_barrier();
        __builtin_amdgcn_sched_barrier(0);

        if (it + 2 < nk) {
            const int stg = (cur >= 1) ? cur - 1 : cur + 2;   // (cur+2)%3
            STAGE(stg, (it + 2) * 32);
        }

        bf16x8 af[8], bfr[4];
        #pragma unroll
        for (int i = 0; i < 8; ++i)
            af[i]  = *(const bf16x8*)(&As[cur][(wm + i * 16 + l16) * 32 + quad * 8]);
        #pragma unroll
        for (int i = 0; i < 4; ++i)
            bfr[i] = *(const bf16x8*)(&Bs[cur][(wn + i * 16 + l16) * 32 + quad * 8]);
        #pragma unroll
        for (int mi = 0; mi < 8; ++mi)
            #pragma unroll
            for (int ni = 0; ni < 4; ++ni)
                acc[mi][ni] = MFMA16(af[mi], bfr[ni], acc[mi][ni]);

        cur = (cur + 1 >= 3) ? 0 : cur + 1;
    }
#undef STAGE

    #pragma unroll
    for (int ni = 0; ni < 4; ++ni) {
        const int col = bn + wn + ni * 16 + l16;          // 0..3071
        const float bv = bias[col];
        const int which = col >> 10;                      // 0=q 1=k 2=v
        const int c = col & 1023;
        const int h = c >> 6, d = c & 63;
        #pragma unroll
        for (int mi = 0; mi < 8; ++mi)
            #pragma unroll
            for (int r = 0; r < 4; ++r) {
                const int row = bm + wm + mi * 16 + quad * 4 + r;  // 0..8191
                const int bb = row >> 11, tt = row & 2047;
                size_t idx;
                if (which == 2)  // v transposed: [b,h,d,t]
                    idx = 2 * HEADELEMS + ((((size_t)bb * NHEAD + h) * HSZ + d) * TSEQ + tt);
                else
                    idx = (size_t)which * HEADELEMS
                        + ((((size_t)bb * NHEAD + h) * TSEQ + tt) * HSZ + d);
                outp[idx] = (__bf16)(acc[mi][ni][r] + bv);
            }
    }
}

// ---------------------------------------------------------------------------
// Projection GEMM -- pipe + swizzle, DISTINCT non-template body (r11 proven
// compilation shape; control this round). fp32 row-major out + bias.
// ---------------------------------------------------------------------------
__global__ __launch_bounds__(256, 3)
void gemm_prj_pipe(const __bf16* __restrict__ A, const __bf16* __restrict__ BT,
                   const float* __restrict__ bias, float* __restrict__ outp,
                   int M, int N, int K)
{
    __shared__ __bf16 As[3][128 * 32];
    __shared__ __bf16 Bs[3][128 * 32];

    const int t    = threadIdx.x;
    const int wave = t >> 6, lane = t & 63;
    const int quad = lane >> 4, l16 = lane & 15;

    const int nbx = (int)gridDim.x;
    int lin = (int)blockIdx.y * nbx + (int)blockIdx.x;
    {
        const int cpx = (nbx * (int)gridDim.y) >> 3;   // nwg % 8 == 0
        lin = (lin & 7) * cpx + (lin >> 3);
    }
    const int bm = (lin / nbx) * 128, bn = (lin % nbx) * 128;
    const int wm = (wave >> 1) * 64, wn = (wave & 1) * 64;

    const int lrow = lane >> 2, lchunk = lane & 3;

    f32x4 acc[4][4];
    #pragma unroll
    for (int i = 0; i < 4; ++i)
        #pragma unroll
        for (int j = 0; j < 4; ++j)
            acc[i][j] = (f32x4){0.f, 0.f, 0.f, 0.f};

    const int c0 = wave * 2, c1 = wave * 2 + 1;
    const __bf16* a0 = A  + (size_t)(bm + 16 * c0 + lrow) * K + 8 * lchunk;
    const __bf16* a1 = A  + (size_t)(bm + 16 * c1 + lrow) * K + 8 * lchunk;
    const __bf16* b0 = BT + (size_t)(bn + 16 * c0 + lrow) * K + 8 * lchunk;
    const __bf16* b1 = BT + (size_t)(bn + 16 * c1 + lrow) * K + 8 * lchunk;

    const int nk = K >> 5;

#define STAGE(buf, kofs) do { \
    load_lds_128(a0 + (kofs), &As[buf][c0 * 512]); \
    load_lds_128(a1 + (kofs), &As[buf][c1 * 512]); \
    load_lds_128(b0 + (kofs), &Bs[buf][c0 * 512]); \
    load_lds_128(b1 + (kofs), &Bs[buf][c1 * 512]); } while (0)

    STAGE(0, 0);
    if (nk > 1) STAGE(1, 32);

    int cur = 0;
    for (int it = 0; it < nk; ++it) {
        if (it + 1 < nk) asm volatile("s_waitcnt vmcnt(4)" ::: "memory");
        else             asm volatile("s_waitcnt vmcnt(0)" ::: "memory");
        __builtin_amdgcn_s_barrier();
        __builtin_amdgcn_sched_barrier(0);

        if (it + 2 < nk) {
            const int stg = (cur >= 1) ? cur - 1 : cur + 2;   // (cur+2)%3
            STAGE(stg, (it + 2) * 32);
        }

        bf16x8 af[4], bfr[4];
        #pragma unroll
        for (int i = 0; i < 4; ++i)
            af[i]  = *(const bf16x8*)(&As[cur][(wm + i * 16 + l16) * 32 + quad * 8]);
        #pragma unroll
        for (int i = 0; i < 4; ++i)
            bfr[i] = *(const bf16x8*)(&Bs[cur][(wn + i * 16 + l16) * 32 + quad * 8]);
        #pragma unroll
        for (int mi = 0; mi < 4; ++mi)
            #pragma unroll
            for (int ni = 0; ni < 4; ++ni)
                acc[mi][ni] = MFMA16(af[mi], bfr[ni], acc[mi][ni]);

        cur = (cur + 1 >= 3) ? 0 : cur + 1;
    }
#undef STAGE

    #pragma unroll
    for (int ni = 0; ni < 4; ++ni) {
        const int col = bn + wn + ni * 16 + l16;
        const float bv = bias[col];
        #pragma unroll
        for (int mi = 0; mi < 4; ++mi)
            #pragma unroll
            for (int r = 0; r < 4; ++r) {
                const int row = bm + wm + mi * 16 + quad * 4 + r;
                outp[(size_t)row * N + col] = acc[mi][ni][r] + bv;
            }
    }
}

// ---------------------------------------------------------------------------
// Flash attention (causal), UNNORMALIZED, S^T formulation -- FROZEN r0/r5
// structure (92.5 us). Four restructures regressed; see r8 notes.
// Q,K: [B*NH, T, 64]; V: [B*NH, 64, T] (transposed). Y: [B,T,C] bf16.
// ---------------------------------------------------------------------------
__global__ __launch_bounds__(256, 4)
void flash_attn(const __bf16* __restrict__ Q, const __bf16* __restrict__ Kg,
                const __bf16* __restrict__ Vg, __bf16* __restrict__ Y)
{
    __shared__ __bf16 Ks[64 * LDF];      // [key][d]
    __shared__ __bf16 Vs[64 * LDF];      // [d][key]
    __shared__ __bf16 Ps[4][32 * LDF];   // per-wave [q][key] (wave-private)

    const int t = threadIdx.x, wave = t >> 6, lane = t & 63;
    const int quad = lane >> 4, l16 = lane & 15;
    const int bh = blockIdx.x;
    const int q0 = ((int)gridDim.y - 1 - (int)blockIdx.y) * 128;  // longest first
    const size_t base = (size_t)bh * TSEQ * HSZ;

    const float sc = 0.125f * 1.44269504088896341f;  // log2(e)/sqrt(HS)

    // Q fragments (B-operand: n=l16 -> q row), pre-scaled by sc
    bf16x8 qf[2][2];
    #pragma unroll
    for (int mi = 0; mi < 2; ++mi) {
        const int qrow = q0 + wave * 32 + mi * 16 + l16;
        #pragma unroll
        for (int h = 0; h < 2; ++h) {
            bf16x8 raw = *(const bf16x8*)(Q + base + (size_t)qrow * HSZ + h * 32 + quad * 8);
            #pragma unroll
            for (int j = 0; j < 8; ++j) qf[mi][h][j] = (__bf16)((float)raw[j] * sc);
        }
    }

    bf16x8 ones;
    #pragma unroll
    for (int j = 0; j < 8; ++j) ones[j] = (__bf16)1.0f;

    f32x4 oacc[2][4];   // [mi][dt], C-layout row=q(quad*4+r), col=d(l16)
    f32x4 lacc[2];      // [mi],     row=q(quad*4+r), all cols equal
    #pragma unroll
    for (int mi = 0; mi < 2; ++mi) {
        lacc[mi] = (f32x4){0.f, 0.f, 0.f, 0.f};
        #pragma unroll
        for (int dt = 0; dt < 4; ++dt) oacc[mi][dt] = (f32x4){0.f, 0.f, 0.f, 0.f};
    }

    const int s_row = t >> 2, s_c16 = (t & 3) * 16;

    const int iters = q0 / 64 + 2;
    for (int it = 0; it < iters; ++it) {
        const int kt = it * 64;
        {   // stage K [key][d]
            const __bf16* kp = Kg + base + (size_t)(kt + s_row) * HSZ + s_c16;
            bf16x8 v0 = *(const bf16x8*)kp;
            bf16x8 v1 = *(const bf16x8*)(kp + 8);
            *(bf16x8*)(&Ks[s_row * LDF + s_c16])     = v0;
            *(bf16x8*)(&Ks[s_row * LDF + s_c16 + 8]) = v1;
        }
        {   // stage V [d][key]
            const __bf16* vp = Vg + base + (size_t)s_row * TSEQ + kt + s_c16;
            bf16x8 v0 = *(const bf16x8*)vp;
            bf16x8 v1 = *(const bf16x8*)(vp + 8);
            *(bf16x8*)(&Vs[s_row * LDF + s_c16])     = v0;
            *(bf16x8*)(&Vs[s_row * LDF + s_c16 + 8]) = v1;
        }
        __syncthreads();

        const bool active = (kt <= q0 + wave * 32 + 31);
        if (active) {
            // ---- S^T = K·Q^T : [4 key-tiles][2 q-tiles], C row=key, col=q ----
            f32x4 st[4][2];
            #pragma unroll
            for (int ktl = 0; ktl < 4; ++ktl) {
                bf16x8 kf0 = *(const bf16x8*)(&Ks[(ktl * 16 + l16) * LDF + quad * 8]);
                bf16x8 kf1 = *(const bf16x8*)(&Ks[(ktl * 16 + l16) * LDF + 32 + quad * 8]);
                #pragma unroll
                for (int mi = 0; mi < 2; ++mi) {
                    f32x4 a = (f32x4){0.f, 0.f, 0.f, 0.f};
                    a = MFMA16(kf0, qf[mi][0], a);
                    a = MFMA16(kf1, qf[mi][1], a);
                    st[ktl][mi] = a;
                }
            }

            // ---- causal mask (near diagonal only) ----
            if (kt + 63 >= q0 + wave * 32) {
                #pragma unroll
                for (int ktl = 0; ktl < 4; ++ktl)
                    #pragma unroll
                    for (int mi = 0; mi < 2; ++mi)
                        #pragma unroll
                        for (int r = 0; r < 4; ++r) {
                            const int key = kt + ktl * 16 + quad * 4 + r;
                            const int qr  = q0 + wave * 32 + mi * 16 + l16;
                            if (key > qr) st[ktl][mi][r] = -1e30f;
                        }
            }

            // ---- P = exp2(S^T), packed b64 writes into Ps[q][key] ----
            #pragma unroll
            for (int ktl = 0; ktl < 4; ++ktl)
                #pragma unroll
                for (int mi = 0; mi < 2; ++mi) {
                    bf16x4 pv;
                    #pragma unroll
                    for (int r = 0; r < 4; ++r)
                        pv[r] = (__bf16)exp2f(st[ktl][mi][r]);
                    *(bf16x4*)(&Ps[wave][(mi * 16 + l16) * LDF + ktl * 16 + quad * 4]) = pv;
                }

            // wave-local fence: DS writes complete before reload (wave-private Ps)
            asm volatile("s_waitcnt lgkmcnt(0)" ::: "memory");

            // ---- O += P·V^T, l += P·1 ----
            bf16x8 pf[2][2];
            #pragma unroll
            for (int mi = 0; mi < 2; ++mi) {
                pf[mi][0] = *(const bf16x8*)(&Ps[wave][(mi * 16 + l16) * LDF + quad * 8]);
                pf[mi][1] = *(const bf16x8*)(&Ps[wave][(mi * 16 + l16) * LDF + 32 + quad * 8]);
                lacc[mi] = MFMA16(pf[mi][0], ones, lacc[mi]);
                lacc[mi] = MFMA16(pf[mi][1], ones, lacc[mi]);
            }
            #pragma unroll
            for (int dt = 0; dt < 4; ++dt) {
                bf16x8 vf0 = *(const bf16x8*)(&Vs[(dt * 16 + l16) * LDF + quad * 8]);
                bf16x8 vf1 = *(const bf16x8*)(&Vs[(dt * 16 + l16) * LDF + 32 + quad * 8]);
                #pragma unroll
                for (int mi = 0; mi < 2; ++mi) {
                    oacc[mi][dt] = MFMA16(pf[mi][0], vf0, oacc[mi][dt]);
                    oacc[mi][dt] = MFMA16(pf[mi][1], vf1, oacc[mi][dt]);
                }
            }
        }
        __syncthreads();
    }

    // ---- epilogue: y = O / l (both C-layout, no cross-lane moves) ----
    const int b = bh >> 4, h = bh & 15;
    #pragma unroll
    for (int mi = 0; mi < 2; ++mi) {
        const f32x4 linv = {1.f / lacc[mi][0], 1.f / lacc[mi][1],
                            1.f / lacc[mi][2], 1.f / lacc[mi][3]};
        #pragma unroll
        for (int dt = 0; dt < 4; ++dt)
            #pragma unroll
            for (int r = 0; r < 4; ++r) {
                const int tt = q0 + wave * 32 + mi * 16 + quad * 4 + r;
                const int d  = dt * 16 + l16;
                Y[((size_t)(b * TSEQ + tt) * CDIM) + h * HSZ + d] =
                    (__bf16)(oacc[mi][dt][r] * linv[r]);
            }
    }
}

// ---------------------------------------------------------------------------
extern "C" void kernel_launch(void* const* d_in, const int* in_sizes, int n_in,
                              void* d_out, int out_size, void* d_ws, size_t ws_size,
                              hipStream_t stream)
{
    const int NX = 8388608, NWA = 3145728, NWP = 1048576;
    char* wsb = (char*)d_ws;

    size_t off = 0;
    __bf16* cx   = (__bf16*)(wsb + off); off += (size_t)2 * NX;
    __bf16* cwaT = (__bf16*)(wsb + off); off += (size_t)2 * NWA;   // [3072][1024]
    __bf16* cwpT = (__bf16*)(wsb + off); off += (size_t)2 * NWP;   // [1024][1024]
    __bf16* q    = (__bf16*)(wsb + off);
    __bf16* y    = q + 3 * HEADELEMS;

    const float* xf = (const float*)d_in[0];
    const float* ba = (const float*)d_in[2];
    const float* bp = (const float*)d_in[4];

    // fused prep: convert x + transpose both weight matrices (one dispatch)
    prep_fused<<<8192, 256, 0, stream>>>(
        xf, cx, (const float*)d_in[1], cwaT, (const float*)d_in[3], cwpT);

    // qkv = x @ W_attn + b_attn -> q/k [b,h,t,d], v [b,h,d,t]
    // (256x128 tile, per-wave 128x64 -- r12 LDS-BW experiment)
    gemm_qkv_pipe<<<dim3(3 * CDIM / 128, BATCH * TSEQ / 256), 256, 0, stream>>>(
        cx, cwaT, ba, q, BATCH * TSEQ, 3 * CDIM, CDIM);

    // causal flash attention -> y [B,T,C] bf16 (frozen r0 structure)
    flash_attn<<<dim3(BATCH * NHEAD, TSEQ / 128), 256, 0, stream>>>(
        q, q + HEADELEMS, q + 2 * HEADELEMS, y);

    // out = y @ W_proj + b_proj (fp32 out)
    gemm_prj_pipe<<<dim3(CDIM / 128, BATCH * TSEQ / 128), 256, 0, stream>>>(
        y, cwpT, bp, (float*)d_out, BATCH * TSEQ, CDIM, CDIM);
}

// Round 13
// 269.697 us; speedup vs baseline: 1.0482x; 1.0482x over previous
//
#include <hip/hip_runtime.h>
#include <hip/hip_bf16.h>
#include <stdint.h>

typedef __bf16 bf16x8 __attribute__((ext_vector_type(8)));
typedef __bf16 bf16x4 __attribute__((ext_vector_type(4)));
typedef float  f32x4  __attribute__((ext_vector_type(4)));

#define MFMA16(a, b, c) __builtin_amdgcn_mfma_f32_16x16x32_bf16((a), (b), (c), 0, 0, 0)

constexpr int BATCH = 4;
constexpr int TSEQ  = 2048;
constexpr int CDIM  = 1024;
constexpr int NHEAD = 16;
constexpr int HSZ   = 64;
constexpr size_t HEADELEMS = (size_t)BATCH * NHEAD * TSEQ * HSZ;  // 8388608

constexpr int LDF = 72;  // flash LDS stride (144 B)

// direct global->LDS DMA, 16 B per lane; LDS dest = wave-uniform base + lane*16
__device__ __forceinline__ void load_lds_128(const __bf16* g, __bf16* l) {
    __builtin_amdgcn_global_load_lds(
        (const __attribute__((address_space(1))) unsigned int*)g,
        (__attribute__((address_space(3))) unsigned int*)l,
        16, 0, 0);
}

// ---------------------------------------------------------------------------
// Fused prep (VALIDATED r10): one dispatch = {fp32->bf16 convert of x,
// W_attn transpose, W_proj transpose}. Grid sections, whole blocks per
// branch, no divergence.
// ---------------------------------------------------------------------------
__global__ __launch_bounds__(256)
void prep_fused(const float* __restrict__ x, __bf16* __restrict__ cx,
                const float* __restrict__ wa, __bf16* __restrict__ cwaT,
                const float* __restrict__ wp, __bf16* __restrict__ cwpT)
{
    __shared__ __bf16 tile[32][33];
    const int blk = blockIdx.x;

    if (blk < 4096) {
        const int i0 = (blk * 256 + (int)threadIdx.x) * 8;   // < 8388608
        float4 a = *(const float4*)(x + i0);
        float4 b = *(const float4*)(x + i0 + 4);
        bf16x8 o;
        o[0] = (__bf16)a.x; o[1] = (__bf16)a.y; o[2] = (__bf16)a.z; o[3] = (__bf16)a.w;
        o[4] = (__bf16)b.x; o[5] = (__bf16)b.y; o[6] = (__bf16)b.z; o[7] = (__bf16)b.w;
        *(bf16x8*)(cx + i0) = o;
        return;
    }

    const float* src;  __bf16* dst;  int K, N, bidx;
    if (blk < 7168) { src = wa; dst = cwaT; K = 1024; N = 3072; bidx = blk - 4096; }
    else            { src = wp; dst = cwpT; K = 1024; N = 1024; bidx = blk - 7168; }
    const int nbx = N >> 5;
    const int n0 = (bidx % nbx) * 32, k0 = (bidx / nbx) * 32;
    const int tx = threadIdx.x & 31, ty = threadIdx.x >> 5;   // 32 x 8
    #pragma unroll
    for (int i = 0; i < 32; i += 8)
        tile[ty + i][tx] = (__bf16)src[(size_t)(k0 + ty + i) * N + n0 + tx];  // tile[k][n]
    __syncthreads();
    #pragma unroll
    for (int i = 0; i < 32; i += 8)
        dst[(size_t)(n0 + ty + i) * K + k0 + tx] = tile[tx][ty + i];          // dst[n][k]
}

// ---------------------------------------------------------------------------
// QKV GEMM -- EXACT r11 body (measured 94.0 us, MfmaUtil 22.3). The r12
// 256x128-tile variant regressed to 116 us (Occ 14.5% -- latency-bound, not
// LDS-BW-bound; tile-ratio lever CLOSED, 64x64/wave @ 3 blocks/CU is the
// sweet spot). m97 + counted-vmcnt pipe + T1 XCD swizzle, distinct
// non-template body (rule-19). 3 LDS buffers, depth-2 prefetch, vmcnt(4)
// per iter (never 0 mid-loop), raw s_barrier + sched_barrier(0).
// Epilogue: scatter q[b,h,t,d], k[b,h,t,d], v transposed [b,h,d,t] (bf16).
// ---------------------------------------------------------------------------
__global__ __launch_bounds__(256, 3)
void gemm_qkv_pipe(const __bf16* __restrict__ A, const __bf16* __restrict__ BT,
                   const float* __restrict__ bias, __bf16* __restrict__ outp,
                   int M, int N, int K)
{
    __shared__ __bf16 As[3][128 * 32];   // [buf][row][k], unpadded
    __shared__ __bf16 Bs[3][128 * 32];

    const int t    = threadIdx.x;
    const int wave = t >> 6, lane = t & 63;
    const int quad = lane >> 4, l16 = lane & 15;

    // T1 XCD swizzle: hw-dispatch id -> logical tile id, contiguous per XCD
    const int nbx = (int)gridDim.x;
    int lin = (int)blockIdx.y * nbx + (int)blockIdx.x;
    {
        const int cpx = (nbx * (int)gridDim.y) >> 3;   // nwg % 8 == 0
        lin = (lin & 7) * cpx + (lin >> 3);
    }
    const int bm = (lin / nbx) * 128, bn = (lin % nbx) * 128;
    const int wm = (wave >> 1) * 64, wn = (wave & 1) * 64;

    const int lrow = lane >> 2, lchunk = lane & 3;

    f32x4 acc[4][4];
    #pragma unroll
    for (int i = 0; i < 4; ++i)
        #pragma unroll
        for (int j = 0; j < 4; ++j)
            acc[i][j] = (f32x4){0.f, 0.f, 0.f, 0.f};

    const int c0 = wave * 2, c1 = wave * 2 + 1;
    const __bf16* a0 = A  + (size_t)(bm + 16 * c0 + lrow) * K + 8 * lchunk;
    const __bf16* a1 = A  + (size_t)(bm + 16 * c1 + lrow) * K + 8 * lchunk;
    const __bf16* b0 = BT + (size_t)(bn + 16 * c0 + lrow) * K + 8 * lchunk;
    const __bf16* b1 = BT + (size_t)(bn + 16 * c1 + lrow) * K + 8 * lchunk;

    const int nk = K >> 5;

#define STAGE(buf, kofs) do { \
    load_lds_128(a0 + (kofs), &As[buf][c0 * 512]); \
    load_lds_128(a1 + (kofs), &As[buf][c1 * 512]); \
    load_lds_128(b0 + (kofs), &Bs[buf][c0 * 512]); \
    load_lds_128(b1 + (kofs), &Bs[buf][c1 * 512]); } while (0)

    // prologue: tiles 0 and 1 in flight
    STAGE(0, 0);
    if (nk > 1) STAGE(1, 32);

    int cur = 0;
    for (int it = 0; it < nk; ++it) {
        if (it + 1 < nk) asm volatile("s_waitcnt vmcnt(4)" ::: "memory");
        else             asm volatile("s_waitcnt vmcnt(0)" ::: "memory");
        __builtin_amdgcn_s_barrier();
        __builtin_amdgcn_sched_barrier(0);

        if (it + 2 < nk) {
            const int stg = (cur >= 1) ? cur - 1 : cur + 2;   // (cur+2)%3
            STAGE(stg, (it + 2) * 32);
        }

        bf16x8 af[4], bfr[4];
        #pragma unroll
        for (int i = 0; i < 4; ++i)
            af[i]  = *(const bf16x8*)(&As[cur][(wm + i * 16 + l16) * 32 + quad * 8]);
        #pragma unroll
        for (int i = 0; i < 4; ++i)
            bfr[i] = *(const bf16x8*)(&Bs[cur][(wn + i * 16 + l16) * 32 + quad * 8]);
        #pragma unroll
        for (int mi = 0; mi < 4; ++mi)
            #pragma unroll
            for (int ni = 0; ni < 4; ++ni)
                acc[mi][ni] = MFMA16(af[mi], bfr[ni], acc[mi][ni]);

        cur = (cur + 1 >= 3) ? 0 : cur + 1;
    }
#undef STAGE

    #pragma unroll
    for (int ni = 0; ni < 4; ++ni) {
        const int col = bn + wn + ni * 16 + l16;          // 0..3071
        const float bv = bias[col];
        const int which = col >> 10;                      // 0=q 1=k 2=v
        const int c = col & 1023;
        const int h = c >> 6, d = c & 63;
        #pragma unroll
        for (int mi = 0; mi < 4; ++mi)
            #pragma unroll
            for (int r = 0; r < 4; ++r) {
                const int row = bm + wm + mi * 16 + quad * 4 + r;  // 0..8191
                const int bb = row >> 11, tt = row & 2047;
                size_t idx;
                if (which == 2)  // v transposed: [b,h,d,t]
                    idx = 2 * HEADELEMS + ((((size_t)bb * NHEAD + h) * HSZ + d) * TSEQ + tt);
                else
                    idx = (size_t)which * HEADELEMS
                        + ((((size_t)bb * NHEAD + h) * TSEQ + tt) * HSZ + d);
                outp[idx] = (__bf16)(acc[mi][ni][r] + bv);
            }
    }
}

// ---------------------------------------------------------------------------
// Projection GEMM -- pipe + swizzle, DISTINCT non-template body (r11 proven;
// control). fp32 row-major out + bias.
// ---------------------------------------------------------------------------
__global__ __launch_bounds__(256, 3)
void gemm_prj_pipe(const __bf16* __restrict__ A, const __bf16* __restrict__ BT,
                   const float* __restrict__ bias, float* __restrict__ outp,
                   int M, int N, int K)
{
    __shared__ __bf16 As[3][128 * 32];
    __shared__ __bf16 Bs[3][128 * 32];

    const int t    = threadIdx.x;
    const int wave = t >> 6, lane = t & 63;
    const int quad = lane >> 4, l16 = lane & 15;

    const int nbx = (int)gridDim.x;
    int lin = (int)blockIdx.y * nbx + (int)blockIdx.x;
    {
        const int cpx = (nbx * (int)gridDim.y) >> 3;   // nwg % 8 == 0
        lin = (lin & 7) * cpx + (lin >> 3);
    }
    const int bm = (lin / nbx) * 128, bn = (lin % nbx) * 128;
    const int wm = (wave >> 1) * 64, wn = (wave & 1) * 64;

    const int lrow = lane >> 2, lchunk = lane & 3;

    f32x4 acc[4][4];
    #pragma unroll
    for (int i = 0; i < 4; ++i)
        #pragma unroll
        for (int j = 0; j < 4; ++j)
            acc[i][j] = (f32x4){0.f, 0.f, 0.f, 0.f};

    const int c0 = wave * 2, c1 = wave * 2 + 1;
    const __bf16* a0 = A  + (size_t)(bm + 16 * c0 + lrow) * K + 8 * lchunk;
    const __bf16* a1 = A  + (size_t)(bm + 16 * c1 + lrow) * K + 8 * lchunk;
    const __bf16* b0 = BT + (size_t)(bn + 16 * c0 + lrow) * K + 8 * lchunk;
    const __bf16* b1 = BT + (size_t)(bn + 16 * c1 + lrow) * K + 8 * lchunk;

    const int nk = K >> 5;

#define STAGE(buf, kofs) do { \
    load_lds_128(a0 + (kofs), &As[buf][c0 * 512]); \
    load_lds_128(a1 + (kofs), &As[buf][c1 * 512]); \
    load_lds_128(b0 + (kofs), &Bs[buf][c0 * 512]); \
    load_lds_128(b1 + (kofs), &Bs[buf][c1 * 512]); } while (0)

    STAGE(0, 0);
    if (nk > 1) STAGE(1, 32);

    int cur = 0;
    for (int it = 0; it < nk; ++it) {
        if (it + 1 < nk) asm volatile("s_waitcnt vmcnt(4)" ::: "memory");
        else             asm volatile("s_waitcnt vmcnt(0)" ::: "memory");
        __builtin_amdgcn_s_barrier();
        __builtin_amdgcn_sched_barrier(0);

        if (it + 2 < nk) {
            const int stg = (cur >= 1) ? cur - 1 : cur + 2;   // (cur+2)%3
            STAGE(stg, (it + 2) * 32);
        }

        bf16x8 af[4], bfr[4];
        #pragma unroll
        for (int i = 0; i < 4; ++i)
            af[i]  = *(const bf16x8*)(&As[cur][(wm + i * 16 + l16) * 32 + quad * 8]);
        #pragma unroll
        for (int i = 0; i < 4; ++i)
            bfr[i] = *(const bf16x8*)(&Bs[cur][(wn + i * 16 + l16) * 32 + quad * 8]);
        #pragma unroll
        for (int mi = 0; mi < 4; ++mi)
            #pragma unroll
            for (int ni = 0; ni < 4; ++ni)
                acc[mi][ni] = MFMA16(af[mi], bfr[ni], acc[mi][ni]);

        cur = (cur + 1 >= 3) ? 0 : cur + 1;
    }
#undef STAGE

    #pragma unroll
    for (int ni = 0; ni < 4; ++ni) {
        const int col = bn + wn + ni * 16 + l16;
        const float bv = bias[col];
        #pragma unroll
        for (int mi = 0; mi < 4; ++mi)
            #pragma unroll
            for (int r = 0; r < 4; ++r) {
                const int row = bm + wm + mi * 16 + quad * 4 + r;
                outp[(size_t)row * N + col] = acc[mi][ni][r] + bv;
            }
    }
}

// ---------------------------------------------------------------------------
// Flash attention (causal), UNNORMALIZED, S^T formulation -- FROZEN r0/r5
// structure (92.5 us) + ROUND-13 T5 s_setprio around MFMA clusters.
// T5 mechanism: pays when co-resident waves are at DIFFERENT phases (m191
// attn +4-7%; m190 lockstep GEMM null). Here 4 blocks/CU interleave
// stage/compute phases independently -> scheduler can favor MFMA-issuing
// waves over other blocks' staging waves. Zero structural change.
// Q,K: [B*NH, T, 64]; V: [B*NH, 64, T] (transposed). Y: [B,T,C] bf16.
// ---------------------------------------------------------------------------
__global__ __launch_bounds__(256, 4)
void flash_attn(const __bf16* __restrict__ Q, const __bf16* __restrict__ Kg,
                const __bf16* __restrict__ Vg, __bf16* __restrict__ Y)
{
    __shared__ __bf16 Ks[64 * LDF];      // [key][d]
    __shared__ __bf16 Vs[64 * LDF];      // [d][key]
    __shared__ __bf16 Ps[4][32 * LDF];   // per-wave [q][key] (wave-private)

    const int t = threadIdx.x, wave = t >> 6, lane = t & 63;
    const int quad = lane >> 4, l16 = lane & 15;
    const int bh = blockIdx.x;
    const int q0 = ((int)gridDim.y - 1 - (int)blockIdx.y) * 128;  // longest first
    const size_t base = (size_t)bh * TSEQ * HSZ;

    const float sc = 0.125f * 1.44269504088896341f;  // log2(e)/sqrt(HS)

    // Q fragments (B-operand: n=l16 -> q row), pre-scaled by sc
    bf16x8 qf[2][2];
    #pragma unroll
    for (int mi = 0; mi < 2; ++mi) {
        const int qrow = q0 + wave * 32 + mi * 16 + l16;
        #pragma unroll
        for (int h = 0; h < 2; ++h) {
            bf16x8 raw = *(const bf16x8*)(Q + base + (size_t)qrow * HSZ + h * 32 + quad * 8);
            #pragma unroll
            for (int j = 0; j < 8; ++j) qf[mi][h][j] = (__bf16)((float)raw[j] * sc);
        }
    }

    bf16x8 ones;
    #pragma unroll
    for (int j = 0; j < 8; ++j) ones[j] = (__bf16)1.0f;

    f32x4 oacc[2][4];   // [mi][dt], C-layout row=q(quad*4+r), col=d(l16)
    f32x4 lacc[2];      // [mi],     row=q(quad*4+r), all cols equal
    #pragma unroll
    for (int mi = 0; mi < 2; ++mi) {
        lacc[mi] = (f32x4){0.f, 0.f, 0.f, 0.f};
        #pragma unroll
        for (int dt = 0; dt < 4; ++dt) oacc[mi][dt] = (f32x4){0.f, 0.f, 0.f, 0.f};
    }

    const int s_row = t >> 2, s_c16 = (t & 3) * 16;

    const int iters = q0 / 64 + 2;
    for (int it = 0; it < iters; ++it) {
        const int kt = it * 64;
        {   // stage K [key][d]
            const __bf16* kp = Kg + base + (size_t)(kt + s_row) * HSZ + s_c16;
            bf16x8 v0 = *(const bf16x8*)kp;
            bf16x8 v1 = *(const bf16x8*)(kp + 8);
            *(bf16x8*)(&Ks[s_row * LDF + s_c16])     = v0;
            *(bf16x8*)(&Ks[s_row * LDF + s_c16 + 8]) = v1;
        }
        {   // stage V [d][key]
            const __bf16* vp = Vg + base + (size_t)s_row * TSEQ + kt + s_c16;
            bf16x8 v0 = *(const bf16x8*)vp;
            bf16x8 v1 = *(const bf16x8*)(vp + 8);
            *(bf16x8*)(&Vs[s_row * LDF + s_c16])     = v0;
            *(bf16x8*)(&Vs[s_row * LDF + s_c16 + 8]) = v1;
        }
        __syncthreads();

        const bool active = (kt <= q0 + wave * 32 + 31);
        if (active) {
            // ---- S^T = K·Q^T : [4 key-tiles][2 q-tiles], C row=key, col=q ----
            f32x4 st[4][2];
            __builtin_amdgcn_s_setprio(1);   // T5: favor MFMA-issuing wave
            #pragma unroll
            for (int ktl = 0; ktl < 4; ++ktl) {
                bf16x8 kf0 = *(const bf16x8*)(&Ks[(ktl * 16 + l16) * LDF + quad * 8]);
                bf16x8 kf1 = *(const bf16x8*)(&Ks[(ktl * 16 + l16) * LDF + 32 + quad * 8]);
                #pragma unroll
                for (int mi = 0; mi < 2; ++mi) {
                    f32x4 a = (f32x4){0.f, 0.f, 0.f, 0.f};
                    a = MFMA16(kf0, qf[mi][0], a);
                    a = MFMA16(kf1, qf[mi][1], a);
                    st[ktl][mi] = a;
                }
            }
            __builtin_amdgcn_s_setprio(0);

            // ---- causal mask (near diagonal only) ----
            if (kt + 63 >= q0 + wave * 32) {
                #pragma unroll
                for (int ktl = 0; ktl < 4; ++ktl)
                    #pragma unroll
                    for (int mi = 0; mi < 2; ++mi)
                        #pragma unroll
                        for (int r = 0; r < 4; ++r) {
                            const int key = kt + ktl * 16 + quad * 4 + r;
                            const int qr  = q0 + wave * 32 + mi * 16 + l16;
                            if (key > qr) st[ktl][mi][r] = -1e30f;
                        }
            }

            // ---- P = exp2(S^T), packed b64 writes into Ps[q][key] ----
            #pragma unroll
            for (int ktl = 0; ktl < 4; ++ktl)
                #pragma unroll
                for (int mi = 0; mi < 2; ++mi) {
                    bf16x4 pv;
                    #pragma unroll
                    for (int r = 0; r < 4; ++r)
                        pv[r] = (__bf16)exp2f(st[ktl][mi][r]);
                    *(bf16x4*)(&Ps[wave][(mi * 16 + l16) * LDF + ktl * 16 + quad * 4]) = pv;
                }

            // wave-local fence: DS writes complete before reload (wave-private Ps)
            asm volatile("s_waitcnt lgkmcnt(0)" ::: "memory");

            // ---- O += P·V^T, l += P·1 ----
            bf16x8 pf[2][2];
            __builtin_amdgcn_s_setprio(1);   // T5: favor MFMA-issuing wave
            #pragma unroll
            for (int mi = 0; mi < 2; ++mi) {
                pf[mi][0] = *(const bf16x8*)(&Ps[wave][(mi * 16 + l16) * LDF + quad * 8]);
                pf[mi][1] = *(const bf16x8*)(&Ps[wave][(mi * 16 + l16) * LDF + 32 + quad * 8]);
                lacc[mi] = MFMA16(pf[mi][0], ones, lacc[mi]);
                lacc[mi] = MFMA16(pf[mi][1], ones, lacc[mi]);
            }
            #pragma unroll
            for (int dt = 0; dt < 4; ++dt) {
                bf16x8 vf0 = *(const bf16x8*)(&Vs[(dt * 16 + l16) * LDF + quad * 8]);
                bf16x8 vf1 = *(const bf16x8*)(&Vs[(dt * 16 + l16) * LDF + 32 + quad * 8]);
                #pragma unroll
                for (int mi = 0; mi < 2; ++mi) {
                    oacc[mi][dt] = MFMA16(pf[mi][0], vf0, oacc[mi][dt]);
                    oacc[mi][dt] = MFMA16(pf[mi][1], vf1, oacc[mi][dt]);
                }
            }
            __builtin_amdgcn_s_setprio(0);
        }
        __syncthreads();
    }

    // ---- epilogue: y = O / l (both C-layout, no cross-lane moves) ----
    const int b = bh >> 4, h = bh & 15;
    #pragma unroll
    for (int mi = 0; mi < 2; ++mi) {
        const f32x4 linv = {1.f / lacc[mi][0], 1.f / lacc[mi][1],
                            1.f / lacc[mi][2], 1.f / lacc[mi][3]};
        #pragma unroll
        for (int dt = 0; dt < 4; ++dt)
            #pragma unroll
            for (int r = 0; r < 4; ++r) {
                const int tt = q0 + wave * 32 + mi * 16 + quad * 4 + r;
                const int d  = dt * 16 + l16;
                Y[((size_t)(b * TSEQ + tt) * CDIM) + h * HSZ + d] =
                    (__bf16)(oacc[mi][dt][r] * linv[r]);
            }
    }
}

// ---------------------------------------------------------------------------
extern "C" void kernel_launch(void* const* d_in, const int* in_sizes, int n_in,
                              void* d_out, int out_size, void* d_ws, size_t ws_size,
                              hipStream_t stream)
{
    const int NX = 8388608, NWA = 3145728, NWP = 1048576;
    char* wsb = (char*)d_ws;

    size_t off = 0;
    __bf16* cx   = (__bf16*)(wsb + off); off += (size_t)2 * NX;
    __bf16* cwaT = (__bf16*)(wsb + off); off += (size_t)2 * NWA;   // [3072][1024]
    __bf16* cwpT = (__bf16*)(wsb + off); off += (size_t)2 * NWP;   // [1024][1024]
    __bf16* q    = (__bf16*)(wsb + off);
    __bf16* y    = q + 3 * HEADELEMS;

    const float* xf = (const float*)d_in[0];
    const float* ba = (const float*)d_in[2];
    const float* bp = (const float*)d_in[4];

    // fused prep: convert x + transpose both weight matrices (one dispatch)
    prep_fused<<<8192, 256, 0, stream>>>(
        xf, cx, (const float*)d_in[1], cwaT, (const float*)d_in[3], cwpT);

    // qkv = x @ W_attn + b_attn -> q/k [b,h,t,d], v [b,h,d,t]  (exact r11 body)
    gemm_qkv_pipe<<<dim3(3 * CDIM / 128, BATCH * TSEQ / 128), 256, 0, stream>>>(
        cx, cwaT, ba, q, BATCH * TSEQ, 3 * CDIM, CDIM);

    // causal flash attention -> y [B,T,C] bf16 (frozen structure + T5 setprio)
    flash_attn<<<dim3(BATCH * NHEAD, TSEQ / 128), 256, 0, stream>>>(
        q, q + HEADELEMS, q + 2 * HEADELEMS, y);

    // out = y @ W_proj + b_proj (fp32 out)
    gemm_prj_pipe<<<dim3(CDIM / 128, BATCH * TSEQ / 128), 256, 0, stream>>>(
        y, cwpT, bp, (float*)d_out, BATCH * TSEQ, CDIM, CDIM);
}

// Round 14
// 262.216 us; speedup vs baseline: 1.0781x; 1.0285x over previous
//
#include <hip/hip_runtime.h>
#include <hip/hip_bf16.h>
#include <stdint.h>

typedef __bf16 bf16x8 __attribute__((ext_vector_type(8)));
typedef __bf16 bf16x4 __attribute__((ext_vector_type(4)));
typedef float  f32x4  __attribute__((ext_vector_type(4)));

#define MFMA16(a, b, c) __builtin_amdgcn_mfma_f32_16x16x32_bf16((a), (b), (c), 0, 0, 0)

constexpr int BATCH = 4;
constexpr int TSEQ  = 2048;
constexpr int CDIM  = 1024;
constexpr int NHEAD = 16;
constexpr int HSZ   = 64;
constexpr size_t HEADELEMS = (size_t)BATCH * NHEAD * TSEQ * HSZ;  // 8388608

constexpr int LDF = 72;  // flash LDS stride (144 B)

// direct global->LDS DMA, 16 B per lane; LDS dest = wave-uniform base + lane*16
__device__ __forceinline__ void load_lds_128(const __bf16* g, __bf16* l) {
    __builtin_amdgcn_global_load_lds(
        (const __attribute__((address_space(1))) unsigned int*)g,
        (__attribute__((address_space(3))) unsigned int*)l,
        16, 0, 0);
}

// ---------------------------------------------------------------------------
// Fused prep (VALIDATED r10): one dispatch = {fp32->bf16 convert of x,
// W_attn transpose, W_proj transpose}. Grid sections, whole blocks per
// branch, no divergence.
// ---------------------------------------------------------------------------
__global__ __launch_bounds__(256)
void prep_fused(const float* __restrict__ x, __bf16* __restrict__ cx,
                const float* __restrict__ wa, __bf16* __restrict__ cwaT,
                const float* __restrict__ wp, __bf16* __restrict__ cwpT)
{
    __shared__ __bf16 tile[32][33];
    const int blk = blockIdx.x;

    if (blk < 4096) {
        const int i0 = (blk * 256 + (int)threadIdx.x) * 8;   // < 8388608
        float4 a = *(const float4*)(x + i0);
        float4 b = *(const float4*)(x + i0 + 4);
        bf16x8 o;
        o[0] = (__bf16)a.x; o[1] = (__bf16)a.y; o[2] = (__bf16)a.z; o[3] = (__bf16)a.w;
        o[4] = (__bf16)b.x; o[5] = (__bf16)b.y; o[6] = (__bf16)b.z; o[7] = (__bf16)b.w;
        *(bf16x8*)(cx + i0) = o;
        return;
    }

    const float* src;  __bf16* dst;  int K, N, bidx;
    if (blk < 7168) { src = wa; dst = cwaT; K = 1024; N = 3072; bidx = blk - 4096; }
    else            { src = wp; dst = cwpT; K = 1024; N = 1024; bidx = blk - 7168; }
    const int nbx = N >> 5;
    const int n0 = (bidx % nbx) * 32, k0 = (bidx / nbx) * 32;
    const int tx = threadIdx.x & 31, ty = threadIdx.x >> 5;   // 32 x 8
    #pragma unroll
    for (int i = 0; i < 32; i += 8)
        tile[ty + i][tx] = (__bf16)src[(size_t)(k0 + ty + i) * N + n0 + tx];  // tile[k][n]
    __syncthreads();
    #pragma unroll
    for (int i = 0; i < 32; i += 8)
        dst[(size_t)(n0 + ty + i) * K + k0 + tx] = tile[tx][ty + i];          // dst[n][k]
}

// ---------------------------------------------------------------------------
// QKV GEMM -- FINAL (exact r11 body, measured 94.0 us, MfmaUtil 22.3).
// m97 structure + counted-vmcnt pipeline + T1 XCD swizzle, distinct
// non-template body (rule-19: templating QKV+proj together cost +12%).
// 3 LDS buffers, depth-2 prefetch, vmcnt(4) per iter (never 0 mid-loop),
// raw s_barrier + sched_barrier(0).
// Ordering:
//   - read-after-DMA: tile it's 4 DMAs issued at iter it-2. At iter it's top,
//     outstanding = tiles {it, it+1} = 8 ops; vmcnt(4) drains tile it for
//     this wave; the s_barrier then publishes every wave's tile-it DMAs.
//   - DMA-write-after-read: tile it+2 overwrites buf[(it+2)%3], last read as
//     tile it-1 during iter it-1; staging issue sits AFTER iter it's barrier.
// Session ledger for this structure: 8-phase port (r1), 256x128 tile (r12)
// both regressed -- 64x64/wave @ 3 blocks/CU is this schedule's optimum.
// Epilogue: scatter q[b,h,t,d], k[b,h,t,d], v transposed [b,h,d,t] (bf16).
// ---------------------------------------------------------------------------
__global__ __launch_bounds__(256, 3)
void gemm_qkv_pipe(const __bf16* __restrict__ A, const __bf16* __restrict__ BT,
                   const float* __restrict__ bias, __bf16* __restrict__ outp,
                   int M, int N, int K)
{
    __shared__ __bf16 As[3][128 * 32];   // [buf][row][k], unpadded
    __shared__ __bf16 Bs[3][128 * 32];

    const int t    = threadIdx.x;
    const int wave = t >> 6, lane = t & 63;
    const int quad = lane >> 4, l16 = lane & 15;

    // T1 XCD swizzle: hw-dispatch id -> logical tile id, contiguous per XCD
    // (VALIDATED r9: FETCH_SIZE 71.75 -> 57.5 MB)
    const int nbx = (int)gridDim.x;
    int lin = (int)blockIdx.y * nbx + (int)blockIdx.x;
    {
        const int cpx = (nbx * (int)gridDim.y) >> 3;   // nwg % 8 == 0
        lin = (lin & 7) * cpx + (lin >> 3);
    }
    const int bm = (lin / nbx) * 128, bn = (lin % nbx) * 128;
    const int wm = (wave >> 1) * 64, wn = (wave & 1) * 64;

    const int lrow = lane >> 2, lchunk = lane & 3;

    f32x4 acc[4][4];
    #pragma unroll
    for (int i = 0; i < 4; ++i)
        #pragma unroll
        for (int j = 0; j < 4; ++j)
            acc[i][j] = (f32x4){0.f, 0.f, 0.f, 0.f};

    const int c0 = wave * 2, c1 = wave * 2 + 1;
    const __bf16* a0 = A  + (size_t)(bm + 16 * c0 + lrow) * K + 8 * lchunk;
    const __bf16* a1 = A  + (size_t)(bm + 16 * c1 + lrow) * K + 8 * lchunk;
    const __bf16* b0 = BT + (size_t)(bn + 16 * c0 + lrow) * K + 8 * lchunk;
    const __bf16* b1 = BT + (size_t)(bn + 16 * c1 + lrow) * K + 8 * lchunk;

    const int nk = K >> 5;

#define STAGE(buf, kofs) do { \
    load_lds_128(a0 + (kofs), &As[buf][c0 * 512]); \
    load_lds_128(a1 + (kofs), &As[buf][c1 * 512]); \
    load_lds_128(b0 + (kofs), &Bs[buf][c0 * 512]); \
    load_lds_128(b1 + (kofs), &Bs[buf][c1 * 512]); } while (0)

    // prologue: tiles 0 and 1 in flight
    STAGE(0, 0);
    if (nk > 1) STAGE(1, 32);

    int cur = 0;
    for (int it = 0; it < nk; ++it) {
        if (it + 1 < nk) asm volatile("s_waitcnt vmcnt(4)" ::: "memory");
        else             asm volatile("s_waitcnt vmcnt(0)" ::: "memory");
        __builtin_amdgcn_s_barrier();
        __builtin_amdgcn_sched_barrier(0);

        if (it + 2 < nk) {
            const int stg = (cur >= 1) ? cur - 1 : cur + 2;   // (cur+2)%3
            STAGE(stg, (it + 2) * 32);
        }

        bf16x8 af[4], bfr[4];
        #pragma unroll
        for (int i = 0; i < 4; ++i)
            af[i]  = *(const bf16x8*)(&As[cur][(wm + i * 16 + l16) * 32 + quad * 8]);
        #pragma unroll
        for (int i = 0; i < 4; ++i)
            bfr[i] = *(const bf16x8*)(&Bs[cur][(wn + i * 16 + l16) * 32 + quad * 8]);
        #pragma unroll
        for (int mi = 0; mi < 4; ++mi)
            #pragma unroll
            for (int ni = 0; ni < 4; ++ni)
                acc[mi][ni] = MFMA16(af[mi], bfr[ni], acc[mi][ni]);

        cur = (cur + 1 >= 3) ? 0 : cur + 1;
    }
#undef STAGE

    #pragma unroll
    for (int ni = 0; ni < 4; ++ni) {
        const int col = bn + wn + ni * 16 + l16;          // 0..3071
        const float bv = bias[col];
        const int which = col >> 10;                      // 0=q 1=k 2=v
        const int c = col & 1023;
        const int h = c >> 6, d = c & 63;
        #pragma unroll
        for (int mi = 0; mi < 4; ++mi)
            #pragma unroll
            for (int r = 0; r < 4; ++r) {
                const int row = bm + wm + mi * 16 + quad * 4 + r;  // 0..8191
                const int bb = row >> 11, tt = row & 2047;
                size_t idx;
                if (which == 2)  // v transposed: [b,h,d,t]
                    idx = 2 * HEADELEMS + ((((size_t)bb * NHEAD + h) * HSZ + d) * TSEQ + tt);
                else
                    idx = (size_t)which * HEADELEMS
                        + ((((size_t)bb * NHEAD + h) * TSEQ + tt) * HSZ + d);
                outp[idx] = (__bf16)(acc[mi][ni][r] + bv);
            }
    }
}

// ---------------------------------------------------------------------------
// Projection GEMM -- pipe + swizzle, DISTINCT non-template body (r11 proven).
// fp32 row-major out + bias.
// ---------------------------------------------------------------------------
__global__ __launch_bounds__(256, 3)
void gemm_prj_pipe(const __bf16* __restrict__ A, const __bf16* __restrict__ BT,
                   const float* __restrict__ bias, float* __restrict__ outp,
                   int M, int N, int K)
{
    __shared__ __bf16 As[3][128 * 32];
    __shared__ __bf16 Bs[3][128 * 32];

    const int t    = threadIdx.x;
    const int wave = t >> 6, lane = t & 63;
    const int quad = lane >> 4, l16 = lane & 15;

    const int nbx = (int)gridDim.x;
    int lin = (int)blockIdx.y * nbx + (int)blockIdx.x;
    {
        const int cpx = (nbx * (int)gridDim.y) >> 3;   // nwg % 8 == 0
        lin = (lin & 7) * cpx + (lin >> 3);
    }
    const int bm = (lin / nbx) * 128, bn = (lin % nbx) * 128;
    const int wm = (wave >> 1) * 64, wn = (wave & 1) * 64;

    const int lrow = lane >> 2, lchunk = lane & 3;

    f32x4 acc[4][4];
    #pragma unroll
    for (int i = 0; i < 4; ++i)
        #pragma unroll
        for (int j = 0; j < 4; ++j)
            acc[i][j] = (f32x4){0.f, 0.f, 0.f, 0.f};

    const int c0 = wave * 2, c1 = wave * 2 + 1;
    const __bf16* a0 = A  + (size_t)(bm + 16 * c0 + lrow) * K + 8 * lchunk;
    const __bf16* a1 = A  + (size_t)(bm + 16 * c1 + lrow) * K + 8 * lchunk;
    const __bf16* b0 = BT + (size_t)(bn + 16 * c0 + lrow) * K + 8 * lchunk;
    const __bf16* b1 = BT + (size_t)(bn + 16 * c1 + lrow) * K + 8 * lchunk;

    const int nk = K >> 5;

#define STAGE(buf, kofs) do { \
    load_lds_128(a0 + (kofs), &As[buf][c0 * 512]); \
    load_lds_128(a1 + (kofs), &As[buf][c1 * 512]); \
    load_lds_128(b0 + (kofs), &Bs[buf][c0 * 512]); \
    load_lds_128(b1 + (kofs), &Bs[buf][c1 * 512]); } while (0)

    STAGE(0, 0);
    if (nk > 1) STAGE(1, 32);

    int cur = 0;
    for (int it = 0; it < nk; ++it) {
        if (it + 1 < nk) asm volatile("s_waitcnt vmcnt(4)" ::: "memory");
        else             asm volatile("s_waitcnt vmcnt(0)" ::: "memory");
        __builtin_amdgcn_s_barrier();
        __builtin_amdgcn_sched_barrier(0);

        if (it + 2 < nk) {
            const int stg = (cur >= 1) ? cur - 1 : cur + 2;   // (cur+2)%3
            STAGE(stg, (it + 2) * 32);
        }

        bf16x8 af[4], bfr[4];
        #pragma unroll
        for (int i = 0; i < 4; ++i)
            af[i]  = *(const bf16x8*)(&As[cur][(wm + i * 16 + l16) * 32 + quad * 8]);
        #pragma unroll
        for (int i = 0; i < 4; ++i)
            bfr[i] = *(const bf16x8*)(&Bs[cur][(wn + i * 16 + l16) * 32 + quad * 8]);
        #pragma unroll
        for (int mi = 0; mi < 4; ++mi)
            #pragma unroll
            for (int ni = 0; ni < 4; ++ni)
                acc[mi][ni] = MFMA16(af[mi], bfr[ni], acc[mi][ni]);

        cur = (cur + 1 >= 3) ? 0 : cur + 1;
    }
#undef STAGE

    #pragma unroll
    for (int ni = 0; ni < 4; ++ni) {
        const int col = bn + wn + ni * 16 + l16;
        const float bv = bias[col];
        #pragma unroll
        for (int mi = 0; mi < 4; ++mi)
            #pragma unroll
            for (int r = 0; r < 4; ++r) {
                const int row = bm + wm + mi * 16 + quad * 4 + r;
                outp[(size_t)row * N + col] = acc[mi][ni][r] + bv;
            }
    }
}

// ---------------------------------------------------------------------------
// Flash attention (causal), UNNORMALIZED, S^T formulation -- FINAL frozen
// r0/r5 structure (92.5 us, Occ 28%). Five variants regressed or were null
// (T14 reg-prefetch +7, 2-wave blocks +19, causal pairing +5, split-K +17,
// T5 setprio null) -- this is a robust local optimum for a 4-wave block;
// further headroom needs the co-designed 8-warp/8-phase ladder.
// Q,K: [B*NH, T, 64]; V: [B*NH, 64, T] (transposed). Y: [B,T,C] bf16.
// ---------------------------------------------------------------------------
__global__ __launch_bounds__(256, 4)
void flash_attn(const __bf16* __restrict__ Q, const __bf16* __restrict__ Kg,
                const __bf16* __restrict__ Vg, __bf16* __restrict__ Y)
{
    __shared__ __bf16 Ks[64 * LDF];      // [key][d]
    __shared__ __bf16 Vs[64 * LDF];      // [d][key]
    __shared__ __bf16 Ps[4][32 * LDF];   // per-wave [q][key] (wave-private)

    const int t = threadIdx.x, wave = t >> 6, lane = t & 63;
    const int quad = lane >> 4, l16 = lane & 15;
    const int bh = blockIdx.x;
    const int q0 = ((int)gridDim.y - 1 - (int)blockIdx.y) * 128;  // longest first
    const size_t base = (size_t)bh * TSEQ * HSZ;

    const float sc = 0.125f * 1.44269504088896341f;  // log2(e)/sqrt(HS)

    // Q fragments (B-operand: n=l16 -> q row), pre-scaled by sc
    bf16x8 qf[2][2];
    #pragma unroll
    for (int mi = 0; mi < 2; ++mi) {
        const int qrow = q0 + wave * 32 + mi * 16 + l16;
        #pragma unroll
        for (int h = 0; h < 2; ++h) {
            bf16x8 raw = *(const bf16x8*)(Q + base + (size_t)qrow * HSZ + h * 32 + quad * 8);
            #pragma unroll
            for (int j = 0; j < 8; ++j) qf[mi][h][j] = (__bf16)((float)raw[j] * sc);
        }
    }

    bf16x8 ones;
    #pragma unroll
    for (int j = 0; j < 8; ++j) ones[j] = (__bf16)1.0f;

    f32x4 oacc[2][4];   // [mi][dt], C-layout row=q(quad*4+r), col=d(l16)
    f32x4 lacc[2];      // [mi],     row=q(quad*4+r), all cols equal
    #pragma unroll
    for (int mi = 0; mi < 2; ++mi) {
        lacc[mi] = (f32x4){0.f, 0.f, 0.f, 0.f};
        #pragma unroll
        for (int dt = 0; dt < 4; ++dt) oacc[mi][dt] = (f32x4){0.f, 0.f, 0.f, 0.f};
    }

    const int s_row = t >> 2, s_c16 = (t & 3) * 16;

    const int iters = q0 / 64 + 2;
    for (int it = 0; it < iters; ++it) {
        const int kt = it * 64;
        {   // stage K [key][d]
            const __bf16* kp = Kg + base + (size_t)(kt + s_row) * HSZ + s_c16;
            bf16x8 v0 = *(const bf16x8*)kp;
            bf16x8 v1 = *(const bf16x8*)(kp + 8);
            *(bf16x8*)(&Ks[s_row * LDF + s_c16])     = v0;
            *(bf16x8*)(&Ks[s_row * LDF + s_c16 + 8]) = v1;
        }
        {   // stage V [d][key]
            const __bf16* vp = Vg + base + (size_t)s_row * TSEQ + kt + s_c16;
            bf16x8 v0 = *(const bf16x8*)vp;
            bf16x8 v1 = *(const bf16x8*)(vp + 8);
            *(bf16x8*)(&Vs[s_row * LDF + s_c16])     = v0;
            *(bf16x8*)(&Vs[s_row * LDF + s_c16 + 8]) = v1;
        }
        __syncthreads();

        const bool active = (kt <= q0 + wave * 32 + 31);
        if (active) {
            // ---- S^T = K·Q^T : [4 key-tiles][2 q-tiles], C row=key, col=q ----
            f32x4 st[4][2];
            #pragma unroll
            for (int ktl = 0; ktl < 4; ++ktl) {
                bf16x8 kf0 = *(const bf16x8*)(&Ks[(ktl * 16 + l16) * LDF + quad * 8]);
                bf16x8 kf1 = *(const bf16x8*)(&Ks[(ktl * 16 + l16) * LDF + 32 + quad * 8]);
                #pragma unroll
                for (int mi = 0; mi < 2; ++mi) {
                    f32x4 a = (f32x4){0.f, 0.f, 0.f, 0.f};
                    a = MFMA16(kf0, qf[mi][0], a);
                    a = MFMA16(kf1, qf[mi][1], a);
                    st[ktl][mi] = a;
                }
            }

            // ---- causal mask (near diagonal only) ----
            if (kt + 63 >= q0 + wave * 32) {
                #pragma unroll
                for (int ktl = 0; ktl < 4; ++ktl)
                    #pragma unroll
                    for (int mi = 0; mi < 2; ++mi)
                        #pragma unroll
                        for (int r = 0; r < 4; ++r) {
                            const int key = kt + ktl * 16 + quad * 4 + r;
                            const int qr  = q0 + wave * 32 + mi * 16 + l16;
                            if (key > qr) st[ktl][mi][r] = -1e30f;
                        }
            }

            // ---- P = exp2(S^T), packed b64 writes into Ps[q][key] ----
            #pragma unroll
            for (int ktl = 0; ktl < 4; ++ktl)
                #pragma unroll
                for (int mi = 0; mi < 2; ++mi) {
                    bf16x4 pv;
                    #pragma unroll
                    for (int r = 0; r < 4; ++r)
                        pv[r] = (__bf16)exp2f(st[ktl][mi][r]);
                    *(bf16x4*)(&Ps[wave][(mi * 16 + l16) * LDF + ktl * 16 + quad * 4]) = pv;
                }

            // wave-local fence: DS writes complete before reload (wave-private Ps)
            asm volatile("s_waitcnt lgkmcnt(0)" ::: "memory");

            // ---- O += P·V^T, l += P·1 ----
            bf16x8 pf[2][2];
            #pragma unroll
            for (int mi = 0; mi < 2; ++mi) {
                pf[mi][0] = *(const bf16x8*)(&Ps[wave][(mi * 16 + l16) * LDF + quad * 8]);
                pf[mi][1] = *(const bf16x8*)(&Ps[wave][(mi * 16 + l16) * LDF + 32 + quad * 8]);
                lacc[mi] = MFMA16(pf[mi][0], ones, lacc[mi]);
                lacc[mi] = MFMA16(pf[mi][1], ones, lacc[mi]);
            }
            #pragma unroll
            for (int dt = 0; dt < 4; ++dt) {
                bf16x8 vf0 = *(const bf16x8*)(&Vs[(dt * 16 + l16) * LDF + quad * 8]);
                bf16x8 vf1 = *(const bf16x8*)(&Vs[(dt * 16 + l16) * LDF + 32 + quad * 8]);
                #pragma unroll
                for (int mi = 0; mi < 2; ++mi) {
                    oacc[mi][dt] = MFMA16(pf[mi][0], vf0, oacc[mi][dt]);
                    oacc[mi][dt] = MFMA16(pf[mi][1], vf1, oacc[mi][dt]);
                }
            }
        }
        __syncthreads();
    }

    // ---- epilogue: y = O / l (both C-layout, no cross-lane moves) ----
    const int b = bh >> 4, h = bh & 15;
    #pragma unroll
    for (int mi = 0; mi < 2; ++mi) {
        const f32x4 linv = {1.f / lacc[mi][0], 1.f / lacc[mi][1],
                            1.f / lacc[mi][2], 1.f / lacc[mi][3]};
        #pragma unroll
        for (int dt = 0; dt < 4; ++dt)
            #pragma unroll
            for (int r = 0; r < 4; ++r) {
                const int tt = q0 + wave * 32 + mi * 16 + quad * 4 + r;
                const int d  = dt * 16 + l16;
                Y[((size_t)(b * TSEQ + tt) * CDIM) + h * HSZ + d] =
                    (__bf16)(oacc[mi][dt][r] * linv[r]);
            }
    }
}

// ---------------------------------------------------------------------------
extern "C" void kernel_launch(void* const* d_in, const int* in_sizes, int n_in,
                              void* d_out, int out_size, void* d_ws, size_t ws_size,
                              hipStream_t stream)
{
    const int NX = 8388608, NWA = 3145728, NWP = 1048576;
    char* wsb = (char*)d_ws;

    size_t off = 0;
    __bf16* cx   = (__bf16*)(wsb + off); off += (size_t)2 * NX;
    __bf16* cwaT = (__bf16*)(wsb + off); off += (size_t)2 * NWA;   // [3072][1024]
    __bf16* cwpT = (__bf16*)(wsb + off); off += (size_t)2 * NWP;   // [1024][1024]
    __bf16* q    = (__bf16*)(wsb + off);
    __bf16* y    = q + 3 * HEADELEMS;

    const float* xf = (const float*)d_in[0];
    const float* ba = (const float*)d_in[2];
    const float* bp = (const float*)d_in[4];

    // fused prep: convert x + transpose both weight matrices (one dispatch)
    prep_fused<<<8192, 256, 0, stream>>>(
        xf, cx, (const float*)d_in[1], cwaT, (const float*)d_in[3], cwpT);

    // qkv = x @ W_attn + b_attn -> q/k [b,h,t,d], v [b,h,d,t]
    gemm_qkv_pipe<<<dim3(3 * CDIM / 128, BATCH * TSEQ / 128), 256, 0, stream>>>(
        cx, cwaT, ba, q, BATCH * TSEQ, 3 * CDIM, CDIM);

    // causal flash attention -> y [B,T,C] bf16
    flash_attn<<<dim3(BATCH * NHEAD, TSEQ / 128), 256, 0, stream>>>(
        q, q + HEADELEMS, q + 2 * HEADELEMS, y);

    // out = y @ W_proj + b_proj (fp32 out)
    gemm_prj_pipe<<<dim3(CDIM / 128, BATCH * TSEQ / 128), 256, 0, stream>>>(
        y, cwpT, bp, (float*)d_out, BATCH * TSEQ, CDIM, CDIM);
}